// Round 6
// baseline (86.113 us; speedup 1.0000x reference)
//
#include <hip/hip_runtime.h>
#include <math.h>

#define B_    32
#define S_    2048
#define D_    1024
#define OUT_  4096
#define PB_   32           // s-chunks per batch (kernel 1): 1024 blocks
#define SLOT_ 1032         // floats per partial slot: 8 header + 1024 pacc
#define DSP_  8            // d-splits for GEMM (512 blocks -> 2/CU)
#define CBL_  64           // col-blocks for GEMM (64 pairs each)

typedef float f32x4 __attribute__((ext_vector_type(4)));

// nontemporal loads (nt flag: no-allocate; for streams read exactly once)
__device__ __forceinline__ float4 ntld4(const float* p) {
    f32x4 v = __builtin_nontemporal_load((const f32x4*)p);
    return make_float4(v.x, v.y, v.z, v.w);
}
__device__ __forceinline__ float ntld1(const float* p) {
    return __builtin_nontemporal_load(p);
}

// ---- DPP 16-lane row-sum + readlane cross-group sum (no LDS-pipe traffic) --
template <int CTRL>
__device__ __forceinline__ float dpp_add(float s) {
    int t = __builtin_amdgcn_update_dpp(0, __builtin_bit_cast(int, s),
                                        CTRL, 0xF, 0xF, true);
    return s + __builtin_bit_cast(float, t);
}
__device__ __forceinline__ float rowred16(float s) {
    s = dpp_add<0x128>(s);   // row_ror:8
    s = dpp_add<0x124>(s);   // row_ror:4
    s = dpp_add<0x122>(s);   // row_ror:2
    s = dpp_add<0x121>(s);   // row_ror:1
    return s;                // all 16 lanes of each row hold the row sum
}
__device__ __forceinline__ float xgroup4(float s) {
    float a = __builtin_bit_cast(float, __builtin_amdgcn_readlane(__builtin_bit_cast(int, s),  0));
    float b = __builtin_bit_cast(float, __builtin_amdgcn_readlane(__builtin_bit_cast(int, s), 16));
    float c = __builtin_bit_cast(float, __builtin_amdgcn_readlane(__builtin_bit_cast(int, s), 32));
    float d = __builtin_bit_cast(float, __builtin_amdgcn_readlane(__builtin_bit_cast(int, s), 48));
    return (a + b) + (c + d);
}

// ---------------------------------------------------------------------------
// Kernel 1 (PROVEN 84.4µs version — unchanged): R2 structure + nt x-loads.
// Block = (batch, 64-row s-chunk); wave owns 16 rows as 4 batches of 4 rows.
// 16 independent 1KB loads in flight per batch; 8 independent DPP chains.
// __launch_bounds__(256,4): 16 waves/CU.
// ---------------------------------------------------------------------------
__global__ __launch_bounds__(256, 4) void k_pass1(
    const float* __restrict__ x, const float* __restrict__ ln_w,
    const float* __restrict__ att_w, const float* __restrict__ att_b,
    float* __restrict__ partA)
{
    const int b    = blockIdx.x / PB_;
    const int p    = blockIdx.x % PB_;
    const int tid  = threadIdx.x;
    const int lane = tid & 63;
    const int wv   = tid >> 6;

    float4 av[4];
#pragma unroll
    for (int jj = 0; jj < 4; ++jj) {
        const int d4 = (jj * 64 + lane) * 4;
        float4 lw = *(const float4*)(ln_w + d4);
        float4 aw = *(const float4*)(att_w + d4);
        av[jj] = make_float4(lw.x * aw.x, lw.y * aw.y, lw.z * aw.z, lw.w * aw.w);
    }
    const float ab = att_b[0];

    float  m = -INFINITY, l = 0.f;
    float4 pacc[4];
#pragma unroll
    for (int jj = 0; jj < 4; ++jj) pacc[jj] = make_float4(0.f, 0.f, 0.f, 0.f);

    const int s0 = p * 64 + wv * 16;
    const float* xb = x + ((size_t)b * S_ + s0) * D_;

    for (int pr = 0; pr < 4; ++pr) {
        const float* xr = xb + (size_t)(pr * 4) * D_;
        float4 x0[4], x1[4], x2[4], x3[4];
        float ss0 = 0.f, ss1 = 0.f, ss2 = 0.f, ss3 = 0.f;
        float dt0 = 0.f, dt1 = 0.f, dt2 = 0.f, dt3 = 0.f;
#pragma unroll
        for (int jj = 0; jj < 4; ++jj) {
            const int off = (jj * 64 + lane) * 4;
            x0[jj] = ntld4(xr + off);
            x1[jj] = ntld4(xr + D_ + off);
            x2[jj] = ntld4(xr + 2 * D_ + off);
            x3[jj] = ntld4(xr + 3 * D_ + off);
        }
#pragma unroll
        for (int jj = 0; jj < 4; ++jj) {
            ss0 += x0[jj].x*x0[jj].x + x0[jj].y*x0[jj].y + x0[jj].z*x0[jj].z + x0[jj].w*x0[jj].w;
            dt0 += x0[jj].x*av[jj].x + x0[jj].y*av[jj].y + x0[jj].z*av[jj].z + x0[jj].w*av[jj].w;
            ss1 += x1[jj].x*x1[jj].x + x1[jj].y*x1[jj].y + x1[jj].z*x1[jj].z + x1[jj].w*x1[jj].w;
            dt1 += x1[jj].x*av[jj].x + x1[jj].y*av[jj].y + x1[jj].z*av[jj].z + x1[jj].w*av[jj].w;
            ss2 += x2[jj].x*x2[jj].x + x2[jj].y*x2[jj].y + x2[jj].z*x2[jj].z + x2[jj].w*x2[jj].w;
            dt2 += x2[jj].x*av[jj].x + x2[jj].y*av[jj].y + x2[jj].z*av[jj].z + x2[jj].w*av[jj].w;
            ss3 += x3[jj].x*x3[jj].x + x3[jj].y*x3[jj].y + x3[jj].z*x3[jj].z + x3[jj].w*x3[jj].w;
            dt3 += x3[jj].x*av[jj].x + x3[jj].y*av[jj].y + x3[jj].z*av[jj].z + x3[jj].w*av[jj].w;
        }
        // 16-lane DPP reductions (8 independent chains), then readlane combine
        ss0 = xgroup4(rowred16(ss0)); dt0 = xgroup4(rowred16(dt0));
        ss1 = xgroup4(rowred16(ss1)); dt1 = xgroup4(rowred16(dt1));
        ss2 = xgroup4(rowred16(ss2)); dt2 = xgroup4(rowred16(dt2));
        ss3 = xgroup4(rowred16(ss3)); dt3 = xgroup4(rowred16(dt3));

        const float rr0 = rsqrtf(ss0 * (1.f / (float)D_) + 1e-6f);
        const float rr1 = rsqrtf(ss1 * (1.f / (float)D_) + 1e-6f);
        const float rr2 = rsqrtf(ss2 * (1.f / (float)D_) + 1e-6f);
        const float rr3 = rsqrtf(ss3 * (1.f / (float)D_) + 1e-6f);
        const float sc0 = dt0 * rr0 + ab;
        const float sc1 = dt1 * rr1 + ab;
        const float sc2 = dt2 * rr2 + ab;
        const float sc3 = dt3 * rr3 + ab;
        const float nm  = fmaxf(fmaxf(m, fmaxf(sc0, sc1)), fmaxf(sc2, sc3));
        const float c   = expf(m - nm);          // m=-inf first batch -> 0
        const float w0  = expf(sc0 - nm);
        const float w1  = expf(sc1 - nm);
        const float w2  = expf(sc2 - nm);
        const float w3  = expf(sc3 - nm);
        l = l * c + ((w0 + w1) + (w2 + w3));
        const float a0 = w0 * rr0, a1 = w1 * rr1, a2 = w2 * rr2, a3 = w3 * rr3;
#pragma unroll
        for (int jj = 0; jj < 4; ++jj) {
            float tx = fmaf(x0[jj].x, a0, fmaf(x1[jj].x, a1, fmaf(x2[jj].x, a2, x3[jj].x * a3)));
            float ty = fmaf(x0[jj].y, a0, fmaf(x1[jj].y, a1, fmaf(x2[jj].y, a2, x3[jj].y * a3)));
            float tz = fmaf(x0[jj].z, a0, fmaf(x1[jj].z, a1, fmaf(x2[jj].z, a2, x3[jj].z * a3)));
            float tw = fmaf(x0[jj].w, a0, fmaf(x1[jj].w, a1, fmaf(x2[jj].w, a2, x3[jj].w * a3)));
            pacc[jj].x = fmaf(pacc[jj].x, c, tx);
            pacc[jj].y = fmaf(pacc[jj].y, c, ty);
            pacc[jj].z = fmaf(pacc[jj].z, c, tz);
            pacc[jj].w = fmaf(pacc[jj].w, c, tw);
        }
        m = nm;
    }

    // cross-wave combine in LDS
    __shared__ float s_m[4];
    __shared__ float s_l[4];
    __shared__ float s_pacc[4][D_];
    if (lane == 0) { s_m[wv] = m; s_l[wv] = l; }
#pragma unroll
    for (int jj = 0; jj < 4; ++jj)
        *(float4*)&s_pacc[wv][(jj * 64 + lane) * 4] = pacc[jj];
    __syncthreads();

    const float M = fmaxf(fmaxf(s_m[0], s_m[1]), fmaxf(s_m[2], s_m[3]));
    float  Lg = 0.f;
    float4 acc = make_float4(0.f, 0.f, 0.f, 0.f);
#pragma unroll
    for (int w = 0; w < 4; ++w) {
        const float cc = expf(s_m[w] - M);
        Lg += cc * s_l[w];
        const float4 v = *(const float4*)&s_pacc[w][tid * 4];
        acc.x += cc * v.x; acc.y += cc * v.y; acc.z += cc * v.z; acc.w += cc * v.w;
    }
    float* slot = partA + (size_t)blockIdx.x * SLOT_;
    if (tid == 0) { slot[0] = M; slot[1] = Lg; }
    *(float4*)(slot + 8 + tid * 4) = acc;
}

// ---------------------------------------------------------------------------
// Kernel 2: combine PB_ partials per batch -> pooled[b][d] (with ln_w).
// NEW: nt on partA reads (4.2 MB, read exactly once, mostly cross-XCD).
// ---------------------------------------------------------------------------
__global__ __launch_bounds__(256) void k_combine(
    const float* __restrict__ partA, const float* __restrict__ ln_w,
    float* __restrict__ pooled)
{
    const int b   = blockIdx.x >> 2;
    const int dq  = blockIdx.x & 3;
    const int tid = threadIdx.x;
    const int d   = dq * 256 + tid;
    const float* base = partA + (size_t)b * PB_ * SLOT_;

    float M = -INFINITY;
#pragma unroll 8
    for (int p = 0; p < PB_; ++p) M = fmaxf(M, base[(size_t)p * SLOT_]);

    float Lg = 0.f, acc = 0.f;
    for (int p = 0; p < PB_; ++p) {
        const float* sl = base + (size_t)p * SLOT_;
        const float c = expf(sl[0] - M);
        Lg  += c * ntld1(sl + 1);
        acc += c * ntld1(sl + 8 + d);
    }
    pooled[(size_t)b * D_ + d] = acc / Lg * ln_w[d];
}

// ---------------------------------------------------------------------------
// Kernel 3: partial GEMM, 512 blocks = 8 d-splits x 64 col-blocks (2/CU,
// 8 waves/CU). Alternating-register W prefetch.
// NEW: nt on W loads (32 MB, read exactly once — same mechanism as pass1's x).
// ---------------------------------------------------------------------------
#define LOADW(WV, WG, dq_) do {                                               \
    _Pragma("unroll") for (int i = 0; i < 4; ++i) {                           \
        WV[i] = ntld1(&Wb[(size_t)((dq_) * 4 + i) * (2 * OUT_) + j]);         \
        WG[i] = ntld1(&Wb[(size_t)((dq_) * 4 + i) * (2 * OUT_) + OUT_ + j]);  \
    } } while (0)

#define GFMA(WV, WG, dq_) do {                                                \
    _Pragma("unroll") for (int k = 0; k < 8; ++k) {                           \
        const f32x4 p4 = *(const f32x4*)&sp[g * 8 + k][(dq_) * 4];            \
        accv[k] += p4.x*WV[0] + p4.y*WV[1] + p4.z*WV[2] + p4.w*WV[3];         \
        accg[k] += p4.x*WG[0] + p4.y*WG[1] + p4.z*WG[2] + p4.w*WG[3];         \
    } } while (0)

__global__ __launch_bounds__(256) void k_gemm(
    const float* __restrict__ pooled, const float* __restrict__ W,
    float* __restrict__ partC)
{
    const int cb  = blockIdx.x % CBL_;
    const int ds  = blockIdx.x / CBL_;
    const int tid = threadIdx.x;
    const int j   = tid & 63;
    const int g   = tid >> 6;

    __shared__ float sp[B_][132];           // 128 K-rows of pooled per split
    for (int i = tid; i < B_ * 128; i += 256) {
        const int bb = i >> 7, dd = i & 127;
        sp[bb][dd] = pooled[(size_t)bb * D_ + ds * 128 + dd];
    }
    __syncthreads();

    float accv[8], accg[8];
#pragma unroll
    for (int k = 0; k < 8; ++k) { accv[k] = 0.f; accg[k] = 0.f; }

    const float* Wb = W + (size_t)(ds * 128) * (2 * OUT_) + cb * 64;
    float wva[4], wga[4], wvb[4], wgb[4];
    LOADW(wva, wga, 0);
    for (int h = 0; h < 16; ++h) {          // 32 dq groups, 2 per iteration
        LOADW(wvb, wgb, 2 * h + 1);
        GFMA(wva, wga, 2 * h);
        if (h < 15) LOADW(wva, wga, 2 * h + 2);
        GFMA(wvb, wgb, 2 * h + 1);
    }

#pragma unroll
    for (int k = 0; k < 8; ++k) {
        const int bb = g * 8 + k;
        float* outp = partC + ((size_t)ds * B_ + bb) * (2 * OUT_) + cb * 64;
        outp[j]        = accv[k];
        outp[OUT_ + j] = accg[k];
    }
}

// ---------------------------------------------------------------------------
// Kernel 4: reduce 8 d-splits, add bias, val * gelu(gate) (exact erf form)
// ---------------------------------------------------------------------------
__global__ __launch_bounds__(256) void k_finish(
    const float* __restrict__ partC, const float* __restrict__ gb,
    float* __restrict__ out)
{
    const int idx = blockIdx.x * 256 + threadIdx.x; // < B_*OUT_
    const int b = idx >> 12;
    const int o = idx & (OUT_ - 1);
    float v = gb[o];
    float g = gb[OUT_ + o];
#pragma unroll
    for (int ds = 0; ds < DSP_; ++ds) {
        const float* pc = partC + ((size_t)ds * B_ + b) * (2 * OUT_);
        v += pc[o];
        g += pc[OUT_ + o];
    }
    const float gelu = 0.5f * g * (1.f + erff(g * 0.70710678118654752f));
    out[idx] = v * gelu;
}

extern "C" void kernel_launch(void* const* d_in, const int* in_sizes, int n_in,
                              void* d_out, int out_size, void* d_ws, size_t ws_size,
                              hipStream_t stream) {
    const float* x     = (const float*)d_in[0];
    const float* ln_w  = (const float*)d_in[1];
    const float* att_w = (const float*)d_in[2];
    const float* att_b = (const float*)d_in[3];
    const float* gw    = (const float*)d_in[4];
    const float* gb    = (const float*)d_in[5];
    float* out = (float*)d_out;

    float* ws     = (float*)d_ws;
    float* partA  = ws;                                  // B_*PB_*SLOT_ floats (4.2 MB)
    float* pooled = partA + (size_t)B_ * PB_ * SLOT_;    // B_*D_ floats (128 KB)
    float* partC  = pooled + (size_t)B_ * D_;            // DSP_*B_*2*OUT_ floats (8.4 MB)

    hipLaunchKernelGGL(k_pass1,   dim3(B_ * PB_),          dim3(256), 0, stream,
                       x, ln_w, att_w, att_b, partA);
    hipLaunchKernelGGL(k_combine, dim3(B_ * 4),            dim3(256), 0, stream,
                       partA, ln_w, pooled);
    hipLaunchKernelGGL(k_gemm,    dim3(CBL_ * DSP_),       dim3(256), 0, stream,
                       pooled, gw, partC);
    hipLaunchKernelGGL(k_finish,  dim3((B_ * OUT_) / 256), dim3(256), 0, stream,
                       partC, gb, out);
}

// Round 7
// 83.076 us; speedup vs baseline: 1.0366x; 1.0366x over previous
//
#include <hip/hip_runtime.h>
#include <math.h>

#define B_    32
#define S_    2048
#define D_    1024
#define OUT_  4096
#define PB_   32           // s-chunks per batch (kernel 1): 1024 blocks
#define SLOT_ 1032         // floats per partial slot: 8 header + 1024 pacc
#define DSP_  8            // d-splits for GEMM (512 blocks -> 2/CU)
#define CBL_  64           // col-blocks for GEMM (64 pairs each)

typedef float f32x4 __attribute__((ext_vector_type(4)));

// nontemporal float4 load (nt flag: no-allocate; x is read exactly once)
__device__ __forceinline__ float4 ntld4(const float* p) {
    f32x4 v = __builtin_nontemporal_load((const f32x4*)p);
    return make_float4(v.x, v.y, v.z, v.w);
}

// ---- DPP 16-lane row-sum + readlane cross-group sum (no LDS-pipe traffic) --
template <int CTRL>
__device__ __forceinline__ float dpp_add(float s) {
    int t = __builtin_amdgcn_update_dpp(0, __builtin_bit_cast(int, s),
                                        CTRL, 0xF, 0xF, true);
    return s + __builtin_bit_cast(float, t);
}
__device__ __forceinline__ float rowred16(float s) {
    s = dpp_add<0x128>(s);   // row_ror:8
    s = dpp_add<0x124>(s);   // row_ror:4
    s = dpp_add<0x122>(s);   // row_ror:2
    s = dpp_add<0x121>(s);   // row_ror:1
    return s;                // all 16 lanes of each row hold the row sum
}
__device__ __forceinline__ float xgroup4(float s) {
    float a = __builtin_bit_cast(float, __builtin_amdgcn_readlane(__builtin_bit_cast(int, s),  0));
    float b = __builtin_bit_cast(float, __builtin_amdgcn_readlane(__builtin_bit_cast(int, s), 16));
    float c = __builtin_bit_cast(float, __builtin_amdgcn_readlane(__builtin_bit_cast(int, s), 32));
    float d = __builtin_bit_cast(float, __builtin_amdgcn_readlane(__builtin_bit_cast(int, s), 48));
    return (a + b) + (c + d);
}

// ---------------------------------------------------------------------------
// Kernel 1 (R5 structure; ONLY change: expf -> __expf on the serial tail).
// Block = (batch, 64-row s-chunk); wave owns 16 rows as 4 batches of 4 rows.
// 16 independent 1KB nt loads in flight per batch; 8 independent DPP chains.
// __launch_bounds__(256,4): 16 waves/CU.
// ---------------------------------------------------------------------------
__global__ __launch_bounds__(256, 4) void k_pass1(
    const float* __restrict__ x, const float* __restrict__ ln_w,
    const float* __restrict__ att_w, const float* __restrict__ att_b,
    float* __restrict__ partA)
{
    const int b    = blockIdx.x / PB_;
    const int p    = blockIdx.x % PB_;
    const int tid  = threadIdx.x;
    const int lane = tid & 63;
    const int wv   = tid >> 6;

    float4 av[4];
#pragma unroll
    for (int jj = 0; jj < 4; ++jj) {
        const int d4 = (jj * 64 + lane) * 4;
        float4 lw = *(const float4*)(ln_w + d4);
        float4 aw = *(const float4*)(att_w + d4);
        av[jj] = make_float4(lw.x * aw.x, lw.y * aw.y, lw.z * aw.z, lw.w * aw.w);
    }
    const float ab = att_b[0];

    float  m = -INFINITY, l = 0.f;
    float4 pacc[4];
#pragma unroll
    for (int jj = 0; jj < 4; ++jj) pacc[jj] = make_float4(0.f, 0.f, 0.f, 0.f);

    const int s0 = p * 64 + wv * 16;
    const float* xb = x + ((size_t)b * S_ + s0) * D_;

    for (int pr = 0; pr < 4; ++pr) {
        const float* xr = xb + (size_t)(pr * 4) * D_;
        float4 x0[4], x1[4], x2[4], x3[4];
        float ss0 = 0.f, ss1 = 0.f, ss2 = 0.f, ss3 = 0.f;
        float dt0 = 0.f, dt1 = 0.f, dt2 = 0.f, dt3 = 0.f;
#pragma unroll
        for (int jj = 0; jj < 4; ++jj) {
            const int off = (jj * 64 + lane) * 4;
            x0[jj] = ntld4(xr + off);
            x1[jj] = ntld4(xr + D_ + off);
            x2[jj] = ntld4(xr + 2 * D_ + off);
            x3[jj] = ntld4(xr + 3 * D_ + off);
        }
#pragma unroll
        for (int jj = 0; jj < 4; ++jj) {
            ss0 += x0[jj].x*x0[jj].x + x0[jj].y*x0[jj].y + x0[jj].z*x0[jj].z + x0[jj].w*x0[jj].w;
            dt0 += x0[jj].x*av[jj].x + x0[jj].y*av[jj].y + x0[jj].z*av[jj].z + x0[jj].w*av[jj].w;
            ss1 += x1[jj].x*x1[jj].x + x1[jj].y*x1[jj].y + x1[jj].z*x1[jj].z + x1[jj].w*x1[jj].w;
            dt1 += x1[jj].x*av[jj].x + x1[jj].y*av[jj].y + x1[jj].z*av[jj].z + x1[jj].w*av[jj].w;
            ss2 += x2[jj].x*x2[jj].x + x2[jj].y*x2[jj].y + x2[jj].z*x2[jj].z + x2[jj].w*x2[jj].w;
            dt2 += x2[jj].x*av[jj].x + x2[jj].y*av[jj].y + x2[jj].z*av[jj].z + x2[jj].w*av[jj].w;
            ss3 += x3[jj].x*x3[jj].x + x3[jj].y*x3[jj].y + x3[jj].z*x3[jj].z + x3[jj].w*x3[jj].w;
            dt3 += x3[jj].x*av[jj].x + x3[jj].y*av[jj].y + x3[jj].z*av[jj].z + x3[jj].w*av[jj].w;
        }
        // 16-lane DPP reductions (8 independent chains), then readlane combine
        ss0 = xgroup4(rowred16(ss0)); dt0 = xgroup4(rowred16(dt0));
        ss1 = xgroup4(rowred16(ss1)); dt1 = xgroup4(rowred16(dt1));
        ss2 = xgroup4(rowred16(ss2)); dt2 = xgroup4(rowred16(dt2));
        ss3 = xgroup4(rowred16(ss3)); dt3 = xgroup4(rowred16(dt3));

        const float rr0 = rsqrtf(ss0 * (1.f / (float)D_) + 1e-6f);
        const float rr1 = rsqrtf(ss1 * (1.f / (float)D_) + 1e-6f);
        const float rr2 = rsqrtf(ss2 * (1.f / (float)D_) + 1e-6f);
        const float rr3 = rsqrtf(ss3 * (1.f / (float)D_) + 1e-6f);
        const float sc0 = dt0 * rr0 + ab;
        const float sc1 = dt1 * rr1 + ab;
        const float sc2 = dt2 * rr2 + ab;
        const float sc3 = dt3 * rr3 + ab;
        const float nm  = fmaxf(fmaxf(m, fmaxf(sc0, sc1)), fmaxf(sc2, sc3));
        const float c   = __expf(m - nm);        // m=-inf first batch -> 0
        const float w0  = __expf(sc0 - nm);
        const float w1  = __expf(sc1 - nm);
        const float w2  = __expf(sc2 - nm);
        const float w3  = __expf(sc3 - nm);
        l = l * c + ((w0 + w1) + (w2 + w3));
        const float a0 = w0 * rr0, a1 = w1 * rr1, a2 = w2 * rr2, a3 = w3 * rr3;
#pragma unroll
        for (int jj = 0; jj < 4; ++jj) {
            float tx = fmaf(x0[jj].x, a0, fmaf(x1[jj].x, a1, fmaf(x2[jj].x, a2, x3[jj].x * a3)));
            float ty = fmaf(x0[jj].y, a0, fmaf(x1[jj].y, a1, fmaf(x2[jj].y, a2, x3[jj].y * a3)));
            float tz = fmaf(x0[jj].z, a0, fmaf(x1[jj].z, a1, fmaf(x2[jj].z, a2, x3[jj].z * a3)));
            float tw = fmaf(x0[jj].w, a0, fmaf(x1[jj].w, a1, fmaf(x2[jj].w, a2, x3[jj].w * a3)));
            pacc[jj].x = fmaf(pacc[jj].x, c, tx);
            pacc[jj].y = fmaf(pacc[jj].y, c, ty);
            pacc[jj].z = fmaf(pacc[jj].z, c, tz);
            pacc[jj].w = fmaf(pacc[jj].w, c, tw);
        }
        m = nm;
    }

    // cross-wave combine in LDS
    __shared__ float s_m[4];
    __shared__ float s_l[4];
    __shared__ float s_pacc[4][D_];
    if (lane == 0) { s_m[wv] = m; s_l[wv] = l; }
#pragma unroll
    for (int jj = 0; jj < 4; ++jj)
        *(float4*)&s_pacc[wv][(jj * 64 + lane) * 4] = pacc[jj];
    __syncthreads();

    const float M = fmaxf(fmaxf(s_m[0], s_m[1]), fmaxf(s_m[2], s_m[3]));
    float  Lg = 0.f;
    float4 acc = make_float4(0.f, 0.f, 0.f, 0.f);
#pragma unroll
    for (int w = 0; w < 4; ++w) {
        const float cc = __expf(s_m[w] - M);
        Lg += cc * s_l[w];
        const float4 v = *(const float4*)&s_pacc[w][tid * 4];
        acc.x += cc * v.x; acc.y += cc * v.y; acc.z += cc * v.z; acc.w += cc * v.w;
    }
    float* slot = partA + (size_t)blockIdx.x * SLOT_;
    if (tid == 0) { slot[0] = M; slot[1] = Lg; }
    *(float4*)(slot + 8 + tid * 4) = acc;
}

// ---------------------------------------------------------------------------
// Kernel 2 (R5 structure, plain loads; expf -> __expf on the accum chain):
// combine PB_ partials per batch -> pooled[b][d] (with ln_w).
// 128 blocks = (batch, d-quarter); thread owns one d. Coalesced slot reads.
// ---------------------------------------------------------------------------
__global__ __launch_bounds__(256) void k_combine(
    const float* __restrict__ partA, const float* __restrict__ ln_w,
    float* __restrict__ pooled)
{
    const int b   = blockIdx.x >> 2;
    const int dq  = blockIdx.x & 3;
    const int tid = threadIdx.x;
    const int d   = dq * 256 + tid;
    const float* base = partA + (size_t)b * PB_ * SLOT_;

    float M = -INFINITY;
#pragma unroll 8
    for (int p = 0; p < PB_; ++p) M = fmaxf(M, base[(size_t)p * SLOT_]);

    float Lg = 0.f, acc = 0.f;
    for (int p = 0; p < PB_; ++p) {
        const float* sl = base + (size_t)p * SLOT_;
        const float c = __expf(sl[0] - M);
        Lg  += c * sl[1];
        acc += c * sl[8 + d];
    }
    pooled[(size_t)b * D_ + d] = acc / Lg * ln_w[d];
}

// ---------------------------------------------------------------------------
// Kernel 3 (PROVEN R2/R5 version — nt reverted): partial GEMM, 512 blocks =
// 8 d-splits x 64 col-blocks (2/CU, 8 waves/CU). Alternating-register W
// prefetch.
// ---------------------------------------------------------------------------
#define LOADW(WV, WG, dq_) do {                                               \
    _Pragma("unroll") for (int i = 0; i < 4; ++i) {                           \
        WV[i] = Wb[(size_t)((dq_) * 4 + i) * (2 * OUT_) + j];                 \
        WG[i] = Wb[(size_t)((dq_) * 4 + i) * (2 * OUT_) + OUT_ + j];          \
    } } while (0)

#define GFMA(WV, WG, dq_) do {                                                \
    _Pragma("unroll") for (int k = 0; k < 8; ++k) {                           \
        const f32x4 p4 = *(const f32x4*)&sp[g * 8 + k][(dq_) * 4];            \
        accv[k] += p4.x*WV[0] + p4.y*WV[1] + p4.z*WV[2] + p4.w*WV[3];         \
        accg[k] += p4.x*WG[0] + p4.y*WG[1] + p4.z*WG[2] + p4.w*WG[3];         \
    } } while (0)

__global__ __launch_bounds__(256) void k_gemm(
    const float* __restrict__ pooled, const float* __restrict__ W,
    float* __restrict__ partC)
{
    const int cb  = blockIdx.x % CBL_;
    const int ds  = blockIdx.x / CBL_;
    const int tid = threadIdx.x;
    const int j   = tid & 63;
    const int g   = tid >> 6;

    __shared__ float sp[B_][132];           // 128 K-rows of pooled per split
    for (int i = tid; i < B_ * 128; i += 256) {
        const int bb = i >> 7, dd = i & 127;
        sp[bb][dd] = pooled[(size_t)bb * D_ + ds * 128 + dd];
    }
    __syncthreads();

    float accv[8], accg[8];
#pragma unroll
    for (int k = 0; k < 8; ++k) { accv[k] = 0.f; accg[k] = 0.f; }

    const float* Wb = W + (size_t)(ds * 128) * (2 * OUT_) + cb * 64;
    float wva[4], wga[4], wvb[4], wgb[4];
    LOADW(wva, wga, 0);
    for (int h = 0; h < 16; ++h) {          // 32 dq groups, 2 per iteration
        LOADW(wvb, wgb, 2 * h + 1);
        GFMA(wva, wga, 2 * h);
        if (h < 15) LOADW(wva, wga, 2 * h + 2);
        GFMA(wvb, wgb, 2 * h + 1);
    }

#pragma unroll
    for (int k = 0; k < 8; ++k) {
        const int bb = g * 8 + k;
        float* outp = partC + ((size_t)ds * B_ + bb) * (2 * OUT_) + cb * 64;
        outp[j]        = accv[k];
        outp[OUT_ + j] = accg[k];
    }
}

// ---------------------------------------------------------------------------
// Kernel 4 (unchanged): reduce 8 d-splits, add bias, val * gelu(gate)
// (exact erf form)
// ---------------------------------------------------------------------------
__global__ __launch_bounds__(256) void k_finish(
    const float* __restrict__ partC, const float* __restrict__ gb,
    float* __restrict__ out)
{
    const int idx = blockIdx.x * 256 + threadIdx.x; // < B_*OUT_
    const int b = idx >> 12;
    const int o = idx & (OUT_ - 1);
    float v = gb[o];
    float g = gb[OUT_ + o];
#pragma unroll
    for (int ds = 0; ds < DSP_; ++ds) {
        const float* pc = partC + ((size_t)ds * B_ + b) * (2 * OUT_);
        v += pc[o];
        g += pc[OUT_ + o];
    }
    const float gelu = 0.5f * g * (1.f + erff(g * 0.70710678118654752f));
    out[idx] = v * gelu;
}

extern "C" void kernel_launch(void* const* d_in, const int* in_sizes, int n_in,
                              void* d_out, int out_size, void* d_ws, size_t ws_size,
                              hipStream_t stream) {
    const float* x     = (const float*)d_in[0];
    const float* ln_w  = (const float*)d_in[1];
    const float* att_w = (const float*)d_in[2];
    const float* att_b = (const float*)d_in[3];
    const float* gw    = (const float*)d_in[4];
    const float* gb    = (const float*)d_in[5];
    float* out = (float*)d_out;

    float* ws     = (float*)d_ws;
    float* partA  = ws;                                  // B_*PB_*SLOT_ floats (4.2 MB)
    float* pooled = partA + (size_t)B_ * PB_ * SLOT_;    // B_*D_ floats (128 KB)
    float* partC  = pooled + (size_t)B_ * D_;            // DSP_*B_*2*OUT_ floats (8.4 MB)

    hipLaunchKernelGGL(k_pass1,   dim3(B_ * PB_),          dim3(256), 0, stream,
                       x, ln_w, att_w, att_b, partA);
    hipLaunchKernelGGL(k_combine, dim3(B_ * 4),            dim3(256), 0, stream,
                       partA, ln_w, pooled);
    hipLaunchKernelGGL(k_gemm,    dim3(CBL_ * DSP_),       dim3(256), 0, stream,
                       pooled, gw, partC);
    hipLaunchKernelGGL(k_finish,  dim3((B_ * OUT_) / 256), dim3(256), 0, stream,
                       partC, gb, out);
}